// Round 17
// baseline (48.206 us; speedup 1.0000x reference)
//
#include <hip/hip_runtime.h>
#include <hip/hip_bf16.h>

#define NUM_TYPES 26
#define NPT 128
#define DIMS 256
#define K_TOTAL 3328
#define N_TOK 8192
#define INV_TEMP (1.0f/0.07f)
#define TM 16
#define MAX_TILES 32
#define NHIST 32

typedef unsigned short ushort_t;
typedef short bf16x8 __attribute__((ext_vector_type(8)));
typedef float f32x4 __attribute__((ext_vector_type(4)));

__device__ __forceinline__ float wave_reduce_sum(float v){
#pragma unroll
  for (int off = 32; off; off >>= 1) v += __shfl_xor(v, off);
  return v;
}

__device__ __forceinline__ unsigned short f2bf(float f){
  __hip_bfloat16 h = __float2bfloat16(f);
  return __builtin_bit_cast(unsigned short, h);
}

#define GLOAD_LDS16(g, s) \
  __builtin_amdgcn_global_load_lds((__attribute__((address_space(1))) void*)(g), \
                                   (__attribute__((address_space(3))) void*)(s), 16, 0, 0)

#define VMWAIT(N) do{ asm volatile("s_waitcnt vmcnt(" #N ")" ::: "memory"); \
                      __builtin_amdgcn_sched_barrier(0); }while(0)

// ---------------- prepk: normalize (832) + histogram (32) -------------------
__global__ __launch_bounds__(256) void prepk(const float* __restrict__ E,
                                             const int* __restrict__ Q,
                                             ushort_t* __restrict__ Enb,
                                             int* __restrict__ bh){
  const int t = threadIdx.x;
  const int b = blockIdx.x;
  if (b < 832){
    const int w = t >> 6, l = t & 63;
    const int row = b * 4 + w;
    float4 v = reinterpret_cast<const float4*>(E + (size_t)row * DIMS)[l];
    float ss = v.x*v.x + v.y*v.y + v.z*v.z + v.w*v.w;
    ss = wave_reduce_sum(ss);
    const float inv = 1.0f / sqrtf(ss);
    ushort4 o;
    o.x = f2bf(v.x * inv); o.y = f2bf(v.y * inv);
    o.z = f2bf(v.z * inv); o.w = f2bf(v.w * inv);
    reinterpret_cast<ushort4*>(Enb + (size_t)row * DIMS)[l] = o;
    return;
  }
  {
    __shared__ int h[NUM_TYPES];
    if (t < NUM_TYPES) h[t] = 0;
    __syncthreads();
    const int c = b - 832;
    atomicAdd(&h[Q[c*256 + t]], 1);
    __syncthreads();
    if (t < NUM_TYPES) bh[c*NUM_TYPES + t] = h[t];
  }
}

// ---------------- gramk: Gram upper-tri; scatter+packers on idle blocks -----
__global__ __launch_bounds__(256) void gramk(const float* __restrict__ E,
                                             const ushort_t* __restrict__ Enb,
                                             const int* __restrict__ Q,
                                             const int* __restrict__ bh,
                                             float* __restrict__ EA2,
                                             ushort_t* __restrict__ EC,
                                             int* __restrict__ counts,
                                             int* __restrict__ offsets,
                                             int* __restrict__ perm,
                                             float* __restrict__ part){
  const int bi = blockIdx.y, bj = blockIdx.x;
  const int t = threadIdx.x;
  // one LDS arena aliased by all paths (compute: As/Bs/rs/cs = 34816B; EC pack: T = 33280B)
  __shared__ __align__(16) char sharena[34816];

  if (bi > bj){
    const int lid = bi*(bi-1)/2 + bj;          // 0..350 (bi=26 row: 325+bj)
    if (lid < NHIST){
      // -------- scatter (scan recomputed per block) --------
      __shared__ int sh_tot[NUM_TYPES], sh_off[NUM_TYPES], sh_cur[NUM_TYPES];
      if (t < NUM_TYPES){
        int s = 0;
        for (int h = 0; h < NHIST; ++h) s += bh[h*NUM_TYPES + t];
        sh_tot[t] = s;
      }
      __syncthreads();
      if (t == 0){
        int s = 0;
        for (int g = 0; g < NUM_TYPES; ++g){ sh_off[g] = s; s += sh_tot[g]; }
      }
      __syncthreads();
      if (t < NUM_TYPES){
        int run = sh_off[t];
        for (int h = 0; h < lid; ++h) run += bh[h*NUM_TYPES + t];
        sh_cur[t] = run;
        if (lid == 0){ counts[t] = sh_tot[t]; offsets[t] = sh_off[t]; }
      }
      __syncthreads();
      const int i = lid*256 + t;
      const int q = Q[i];
      const int pos = atomicAdd(&sh_cur[q], 1);
      perm[pos] = i;   // within-type order nondeterministic; per-token outputs invariant
      return;
    }
    if (lid < 136){
      // -------- EC packer (raw E; R16-verbatim logic) --------
      const int id = lid - 32;                 // 0..103
      const int tp = id >> 2, ck = id & 3;
      float (*T)[260] = (float(*)[260])sharena;
      const int row = t >> 3, sub = t & 7;
      const float* src = E + (size_t)(tp*NPT + ck*32 + row) * DIMS;
#pragma unroll
      for (int i = 0; i < 8; ++i){
        const int c4 = sub + 8*i;
        *(f32x4*)(&T[row][c4*4]) = *(const f32x4*)(src + c4*4);
      }
      __syncthreads();
      ushort_t* dst = EC + (size_t)(tp*4 + ck) * 8192;
#pragma unroll
      for (int i = 0; i < 4; ++i){
        const int si = t + i*256;
        const int sec = si >> 8, d = (si >> 2) & 63, s = si & 3;
        const int cb8 = (s ^ ((d >> 1) & 3)) * 8;
        union { bf16x8 v8; ushort_t u[8]; } pk;
#pragma unroll
        for (int j = 0; j < 8; ++j)
          pk.u[j] = f2bf(T[cb8 + j][sec*64 + d]);
        *(bf16x8*)(dst + (size_t)si*8) = pk.v8;
      }
      return;
    }
    if (lid < 344){
      // -------- EA2 packer (raw E; R16-verbatim logic) --------
      const int id = lid - 136;                // 0..207
      const int tp = id >> 3, kt = id & 7;
      float* dst = EA2 + (size_t)tp*32768 + kt*1024;
      const float* src = E + (size_t)tp * NPT * DIMS;
#pragma unroll
      for (int i = 0; i < 16; ++i){
        const int e = i*256 + t;
        const int sec = e >> 10, code = (e >> 3) & 127, j = e & 7;
        dst[sec*8192 + code*8 + j] = src[(size_t)code*DIMS + sec*64 + kt*8 + j];
      }
      return;
    }
    return;
  }

  // -------- Gram compute (R16-verbatim, arena-aliased) --------
  ushort_t* As = (ushort_t*)sharena;                 // 16384
  ushort_t* Bs = (ushort_t*)(sharena + 16384);       // 16384
  float (*rs)[2] = (float(*)[2])(sharena + 32768);   // 1024
  float (*cs)[2] = (float(*)[2])(sharena + 33792);   // 1024
  const int w = t >> 6, l = t & 63;
  const int wr = w >> 1, wc = w & 1;
  const int lrow = l & 15;
  const int lk = (l >> 4) * 8;
  const int hi = l >> 4;

  f32x4 acc[4][4];
#pragma unroll
  for (int m = 0; m < 4; ++m)
#pragma unroll
    for (int n = 0; n < 4; ++n) acc[m][n] = (f32x4){0.f, 0.f, 0.f, 0.f};

  for (int kt = 0; kt < 4; ++kt){
    if (kt) __syncthreads();
#pragma unroll
    for (int p = 0; p < 4; ++p){
      const int cbase = p*256 + w*64;
      const int c = cbase + l;
      const int row = c >> 3;
      const int kcol = (c & 7) * 8;
      const ushort_t* gA = Enb + (size_t)(bi*128 + row) * DIMS + kt*64 + kcol;
      const ushort_t* gB = Enb + (size_t)(bj*128 + row) * DIMS + kt*64 + kcol;
      GLOAD_LDS16(gA, As + (size_t)cbase*8);
      GLOAD_LDS16(gB, Bs + (size_t)cbase*8);
    }
    __syncthreads();
#pragma unroll
    for (int kk = 0; kk < 2; ++kk){
      bf16x8 a[4], b[4];
#pragma unroll
      for (int m = 0; m < 4; ++m)
        a[m] = *reinterpret_cast<const bf16x8*>(&As[(wr*64 + m*16 + lrow)*64 + kk*32 + lk]);
#pragma unroll
      for (int n = 0; n < 4; ++n)
        b[n] = *reinterpret_cast<const bf16x8*>(&Bs[(wc*64 + n*16 + lrow)*64 + kk*32 + lk]);
#pragma unroll
      for (int m = 0; m < 4; ++m)
#pragma unroll
        for (int n = 0; n < 4; ++n)
          acc[m][n] = __builtin_amdgcn_mfma_f32_16x16x32_bf16(a[m], b[n], acc[m][n], 0, 0, 0);
    }
  }

#pragma unroll
  for (int m = 0; m < 4; ++m)
#pragma unroll
    for (int n = 0; n < 4; ++n)
#pragma unroll
      for (int j = 0; j < 4; ++j){
        const int grow = bi*128 + wr*64 + m*16 + hi*4 + j;
        const int gcol = bj*128 + wc*64 + n*16 + lrow;
        const float g = acc[m][n][j];
        acc[m][n][j] = (grow == gcol) ? 0.f : __expf(g * INV_TEMP);
      }

#pragma unroll
  for (int m = 0; m < 4; ++m)
#pragma unroll
    for (int j = 0; j < 4; ++j){
      float s = 0.f;
#pragma unroll
      for (int n = 0; n < 4; ++n) s += acc[m][n][j];
#pragma unroll
      for (int off = 1; off < 16; off <<= 1) s += __shfl_xor(s, off);
      if (lrow == 0) rs[wr*64 + m*16 + hi*4 + j][wc] = s;
    }
  if (bi != bj){
#pragma unroll
    for (int n = 0; n < 4; ++n){
      float c = 0.f;
#pragma unroll
      for (int m = 0; m < 4; ++m)
#pragma unroll
        for (int j = 0; j < 4; ++j) c += acc[m][n][j];
      c += __shfl_xor(c, 16); c += __shfl_xor(c, 32);
      if (hi == 0) cs[wc*64 + n*16 + lrow][wr] = c;
    }
  }
  __syncthreads();
  if (t < 128){
    part[(size_t)bj*K_TOTAL + bi*128 + t] = rs[t][0] + rs[t][1];
    if (bi != bj)
      part[(size_t)bi*K_TOTAL + bj*128 + t] = cs[t][0] + cs[t][1];
  }
}

// ---------------- quantg v17: R16 compute + parallel loss blocks ------------
__device__ __forceinline__ void stageC3(const ushort_t* EC, char* dst, int tp, int ck,
                                        int w, int l){
  const char* src = (const char*)(EC + (size_t)(tp*4 + ck) * 8192) + w*4096;
  char* d = dst + w*4096;
#pragma unroll
  for (int i = 0; i < 4; ++i)
    GLOAD_LDS16(src + i*1024 + l*16, d + i*1024);
}

__global__ __launch_bounds__(256, 4) void quantg(const float* __restrict__ x,
                                                 const float* __restrict__ EA2,
                                                 const ushort_t* __restrict__ EC,
                                                 const float* __restrict__ part,
                                                 const int* __restrict__ counts,
                                                 const int* __restrict__ offsets,
                                                 const int* __restrict__ perm,
                                                 const int* __restrict__ taup,
                                                 float* __restrict__ ppart,
                                                 int* __restrict__ lossCnt,
                                                 float* __restrict__ outZ,
                                                 float* __restrict__ outMisc,
                                                 float* __restrict__ outIdx){
  const int t = threadIdx.x;
  const int tp = blockIdx.x, rb = blockIdx.y;
  __shared__ __align__(16) char arena[37120];

  // ---- parallel uniform-loss blocks: 26 stripes + last-block finalize ----
  if (tp == NUM_TYPES){
    if (rb >= NUM_TYPES) return;
    float a = 0.f;
    if (t < 128){
      const int i = rb*128 + t;
      float s = 0.f;
#pragma unroll
      for (int bb = 0; bb < NUM_TYPES; ++bb) s += part[(size_t)bb*K_TOTAL + i];
      a = logf(s) - logf(part[(size_t)rb*K_TOTAL + i]);
    }
    a = wave_reduce_sum(a);
    float* red = (float*)arena;
    if ((t & 63) == 0 && t < 128) red[t >> 6] = a;
    __syncthreads();
    if (t == 0){
      atomicExch(&ppart[rb], red[0] + red[1]);   // coherent-point store
      __threadfence();
      const int n = atomicAdd(lossCnt, 1);
      if (n == NUM_TYPES - 1){
        float s = 0.f;
#pragma unroll
        for (int bb = 0; bb < NUM_TYPES; ++bb)
          s += atomicAdd(&ppart[bb], 0.0f);      // coherent-point load
        outMisc[0] = 0.f;
        outMisc[1] = s / (float)K_TOTAL;
      }
    }
    return;
  }

  const int cnt = counts[tp];
  if (rb * TM >= cnt) return;
  const int nt = min(TM, cnt - rb * TM);
  const int off = offsets[tp] + rb * TM;

  char* XA = arena;
  char* PB = arena;
  char* BC = arena;
  char* SB = arena + 32768;

  const int w = t >> 6, l = t & 63;
  const int h  = w >> 1;
  const int cg = w & 1;
  const int tx = l & 15, ty = l >> 4;

  const int ti = *taup;
  const float tau = (ti > 0 && ti < (1 << 23)) ? (float)ti : __int_as_float(ti);
  const float inv_tau = 1.0f / tau;

  // ---- stage X (16 rows, 4/wave, source-swizzled) ----
#pragma unroll
  for (int i = 0; i < 4; ++i){
    const int row = w*4 + i;
    const int tid = (row < nt) ? perm[off + row] : perm[off];
    const int sc = (l & 56) | ((l & 7) ^ (row & 7));
    GLOAD_LDS16(x + (size_t)tid*DIMS + sc*4, XA + row*1024);
  }
  __syncthreads();

  // ---- Phase A: f32 dots; 4 rows x 4 codes; B streamed from EA2 ----
  float acc[4][4];
#pragma unroll
  for (int rr = 0; rr < 4; ++rr)
#pragma unroll
    for (int cc = 0; cc < 4; ++cc) acc[rr][cc] = 0.f;

  const float* ea = EA2 + (size_t)tp*32768 + h*16384;
#pragma unroll
  for (int kk = 0; kk < 16; ++kk){
    f32x4 b0[4], b1[4];
#pragma unroll
    for (int cc = 0; cc < 4; ++cc){
      const float* p = ea + (kk >> 3)*8192 + (kk & 7)*1024 + (size_t)(cg*64 + tx + 16*cc)*8;
      b0[cc] = *(const f32x4*)(p);
      b1[cc] = *(const f32x4*)(p + 4);
    }
#pragma unroll
    for (int q = 0; q < 2; ++q){
      f32x4 a[4];
#pragma unroll
      for (int rr = 0; rr < 4; ++rr){
        const int row = rr*4 + ty;
        const int c = (h*32 + kk*2 + q) ^ (row & 7);
        a[rr] = *(const f32x4*)(XA + row*1024 + c*16);
      }
#pragma unroll
      for (int rr = 0; rr < 4; ++rr)
#pragma unroll
        for (int cc = 0; cc < 4; ++cc)
#pragma unroll
          for (int e = 0; e < 4; ++e)
            acc[rr][cc] = fmaf(a[rr][e], (q ? b1 : b0)[cc][e], acc[rr][cc]);
    }
  }
  __syncthreads();

  // ---- per-wave partials PB[h][row][code] ----
#pragma unroll
  for (int rr = 0; rr < 4; ++rr){
    const int row = rr*4 + ty;
#pragma unroll
    for (int cc = 0; cc < 4; ++cc)
      *(float*)(PB + h*8448 + row*528 + (cg*64 + tx + 16*cc)*4) = acc[rr][cc];
  }
  __syncthreads();

  // ---- Phase B: softmax + argmax ----
  {
    const int r = t >> 4, s = t & 15;
    f32x4 v0 = (f32x4){0,0,0,0}, v1 = (f32x4){0,0,0,0};
#pragma unroll
    for (int ww = 0; ww < 2; ++ww){
      v0 += *(const f32x4*)(PB + ww*8448 + r*528 + s*32);
      v1 += *(const f32x4*)(PB + ww*8448 + r*528 + s*32 + 16);
    }
    float v[8];
#pragma unroll
    for (int e = 0; e < 4; ++e){ v[e] = v0[e]*inv_tau; v[4+e] = v1[e]*inv_tau; }
    float m = v[0]; int mi = s*8;
#pragma unroll
    for (int j = 1; j < 8; ++j) if (v[j] > m){ m = v[j]; mi = s*8 + j; }
#pragma unroll
    for (int o = 1; o < 16; o <<= 1){
      const float om = __shfl_xor(m, o);
      const int   oi = __shfl_xor(mi, o);
      if (om > m || (om == m && oi < mi)){ m = om; mi = oi; }
    }
    float e8[8]; float sum = 0.f;
#pragma unroll
    for (int j = 0; j < 8; ++j){ e8[j] = __expf(v[j] - m); sum += e8[j]; }
#pragma unroll
    for (int o = 1; o < 16; o <<= 1) sum += __shfl_xor(sum, o);
    const float inv = 1.0f / sum;
    union { bf16x8 v8; ushort_t u[8]; } pk;
#pragma unroll
    for (int j = 0; j < 8; ++j) pk.u[j] = f2bf(e8[j] * inv);
    *(bf16x8*)(SB + r*272 + s*16) = pk.v8;
    if (s == 0 && r < nt)
      outIdx[perm[off + r]] = (float)(mi + tp * NPT);
  }
  __syncthreads();

  // ---- Phase C: Z = S @ E via MFMA; double-buffered ----
  stageC3(EC, BC, tp, 0, w, l);
  f32x4 zacc[4];
#pragma unroll
  for (int n = 0; n < 4; ++n) zacc[n] = (f32x4){0,0,0,0};
#pragma unroll
  for (int ck = 0; ck < 4; ++ck){
    if (ck < 3) stageC3(EC, BC + ((ck+1)&1)*16384, tp, ck+1, w, l);
    if (ck < 3)      { VMWAIT(4); }
    else             { VMWAIT(0); }
    const bf16x8 af = *(const bf16x8*)(SB + tx*272 + ck*64 + ty*16);
    const char* bbuf = BC + (ck&1)*16384 + w*4096;
#pragma unroll
    for (int n = 0; n < 4; ++n){
      const int d = n*16 + tx;
      const int slot = ty ^ ((d >> 1) & 3);
      const bf16x8 bf = *(const bf16x8*)(bbuf + d*64 + slot*16);
      zacc[n] = __builtin_amdgcn_mfma_f32_16x16x32_bf16(af, bf, zacc[n], 0, 0, 0);
    }
  }
#pragma unroll
  for (int n = 0; n < 4; ++n)
#pragma unroll
    for (int j = 0; j < 4; ++j){
      const int row = ty*4 + j;
      if (row < nt)
        outZ[(size_t)perm[off + row]*DIMS + w*64 + n*16 + tx] = zacc[n][j];
    }
}

extern "C" void kernel_launch(void* const* d_in, const int* in_sizes, int n_in,
                              void* d_out, int out_size, void* d_ws, size_t ws_size,
                              hipStream_t stream){
  const float* x  = (const float*)d_in[0];
  const int*   Q  = (const int*)d_in[1];
  const float* E  = (const float*)d_in[2];
  const int* taup = (const int*)d_in[3];

  float* outZ    = (float*)d_out;
  float* outMisc = outZ + (size_t)N_TOK * DIMS;
  float* outIdx  = outMisc + 2;

  char* wsp = (char*)d_ws;
  ushort_t* Enb = (ushort_t*)wsp;                    // 1,703,936
  float* part   = (float*)(wsp + 1703936);           //   346,112
  float* EA2    = (float*)(wsp + 2050048);           // 3,407,872
  ushort_t* EC  = (ushort_t*)(wsp + 5457920);        // 1,703,936
  int* bh       = (int*)(wsp + 7161856);             //     3,328
  int* counts   = (int*)(wsp + 7165184);
  int* offsets  = (int*)(wsp + 7165312);
  float* ppart  = (float*)(wsp + 7165440);           //       104
  int* lossCnt  = (int*)(wsp + 7165568);             //         4
  int* perm     = (int*)(wsp + 7165696);             //    32,768

  hipMemsetAsync(lossCnt, 0, sizeof(int), stream);
  prepk<<<864, 256, 0, stream>>>(E, Q, Enb, bh);
  gramk<<<dim3(26, 27), 256, 0, stream>>>(E, Enb, Q, bh, EA2, EC,
                                          counts, offsets, perm, part);
  quantg<<<dim3(NUM_TYPES + 1, MAX_TILES), 256, 0, stream>>>(x, EA2, EC, part,
                                                             counts, offsets, perm,
                                                             taup, ppart, lossCnt,
                                                             outZ, outMisc, outIdx);
}